// Round 1
// baseline (800.715 us; speedup 1.0000x reference)
//
#include <hip/hip_runtime.h>
#include <hip/hip_bf16.h>
#include <cstdint>
#include <cstddef>

typedef float  f32x4  __attribute__((ext_vector_type(4)));
typedef __bf16 bf16x8 __attribute__((ext_vector_type(8)));
typedef __bf16 bf16x4 __attribute__((ext_vector_type(4)));

#define N_TOK  8192
#define INDIM  1024
#define DMODEL 512

__device__ __forceinline__ f32x4 mfma16x16x32(bf16x8 a, bf16x8 b, f32x4 c){
  return __builtin_amdgcn_mfma_f32_16x16x32_bf16(a, b, c, 0, 0, 0);
}

// async global->LDS, 16B per lane; lds base must be wave-uniform, dest = base + lane*16
__device__ __forceinline__ void async_copy16(void* lds, const void* g){
  __builtin_amdgcn_global_load_lds((__attribute__((address_space(1))) void*)g,
                                   (__attribute__((address_space(3))) void*)lds,
                                   16, 0, 0);
}

// ---------------- convert / transpose ----------------
__global__ void k_cvt(const float* __restrict__ in, __bf16* __restrict__ out, int n4){
  int stride = gridDim.x * blockDim.x;
  for (int i = blockIdx.x * blockDim.x + threadIdx.x; i < n4; i += stride){
    f32x4 v = ((const f32x4*)in)[i];
    bf16x4 o;
    o[0]=(__bf16)v[0]; o[1]=(__bf16)v[1]; o[2]=(__bf16)v[2]; o[3]=(__bf16)v[3];
    ((bf16x4*)out)[i] = o;
  }
}

// W [Kd][Nd] f32 -> Wt [Nd][Kd] bf16
__global__ void k_tcvt(const float* __restrict__ W, __bf16* __restrict__ Wt, int Kd, int Nd){
  int total = Kd * Nd;
  int stride = gridDim.x * blockDim.x;
  for (int i = blockIdx.x * blockDim.x + threadIdx.x; i < total; i += stride){
    int k = i / Nd, n = i - k * Nd;
    Wt[(size_t)n * Kd + k] = (__bf16)W[i];
  }
}

// ---------------- GEMM: C[M,N] = A[M,K] @ Bt[N,K]^T + bias ----------------
// 128x128 tile, 4 waves, BK=32, single-buffered global_load_lds (m97 structure)
template<int BIAS_ROW>
__global__ __launch_bounds__(256) void k_gemm_bt(
    const __bf16* __restrict__ A, const __bf16* __restrict__ Bt,
    const float* __restrict__ bias, __bf16* __restrict__ C,
    int M, int N, int K)
{
  __shared__ __bf16 Als[128][32];
  __shared__ __bf16 Bls[128][32];
  const int tid = threadIdx.x;
  const int w = tid >> 6, l = tid & 63;
  const int lr = l & 15, lg = l >> 4;
  const int wr = w >> 1, wc = w & 1;
  const int m0 = blockIdx.x * 128, n0 = blockIdx.y * 128;
  const int srow = l >> 2;          // 0..15 within chunk
  const int skof = (l & 3) * 8;     // 0,8,16,24 (bf16 elements)
  f32x4 acc[4][4] = {};
  for (int k0 = 0; k0 < K; k0 += 32){
    #pragma unroll
    for (int i = 0; i < 2; ++i){
      int c = i * 4 + w;  // chunk 0..7, wave-uniform
      async_copy16((char*)&Als[0][0] + c * 1024,
                   A  + (size_t)(m0 + c*16 + srow) * K + k0 + skof);
      async_copy16((char*)&Bls[0][0] + c * 1024,
                   Bt + (size_t)(n0 + c*16 + srow) * K + k0 + skof);
    }
    __syncthreads();
    bf16x8 af[4], bfv[4];
    #pragma unroll
    for (int mf = 0; mf < 4; ++mf) af[mf]  = *(const bf16x8*)&Als[wr*64 + mf*16 + lr][lg*8];
    #pragma unroll
    for (int nf = 0; nf < 4; ++nf) bfv[nf] = *(const bf16x8*)&Bls[wc*64 + nf*16 + lr][lg*8];
    #pragma unroll
    for (int mf = 0; mf < 4; ++mf)
      #pragma unroll
      for (int nf = 0; nf < 4; ++nf)
        acc[mf][nf] = mfma16x16x32(af[mf], bfv[nf], acc[mf][nf]);
    __syncthreads();
  }
  #pragma unroll
  for (int mf = 0; mf < 4; ++mf)
    #pragma unroll
    for (int nf = 0; nf < 4; ++nf)
      #pragma unroll
      for (int r = 0; r < 4; ++r){
        int row = m0 + wr*64 + mf*16 + lg*4 + r;
        int col = n0 + wc*64 + nf*16 + lr;
        float v = acc[mf][nf][r] + (BIAS_ROW ? bias[row] : bias[col]);
        C[(size_t)row * N + col] = (__bf16)v;
      }
}

// ---------------- flash attention ----------------
// BQ=32 rows/block, BK=64 keys/tile, 8 waves. wave w: S-frag (mf=w&1, nf=w>>1),
// PV D-slice d0=w*64. Q in regs, K staged LDS, Vt (=[512][8192]) direct global.
__global__ __launch_bounds__(512) void k_flash(
    const __bf16* __restrict__ Qm, const __bf16* __restrict__ Km,
    const __bf16* __restrict__ Vt, __bf16* __restrict__ ctx)
{
  __shared__ __bf16 Kls[64][512];   // 64 KB
  __shared__ float  Sls[32][64];    // 8 KB
  __shared__ __bf16 Pls[32][64];    // 4 KB
  __shared__ float  mls[32], lls[32], fls[32];
  const int tid = threadIdx.x;
  const int w = tid >> 6, l = tid & 63;
  const int lr = l & 15, lg = l >> 4;
  const int q0 = blockIdx.x * 32;
  const int mf = w & 1, nf = w >> 1;
  const int d0 = w * 64;
  bf16x8 qf[16];
  #pragma unroll
  for (int t = 0; t < 16; ++t)
    qf[t] = *(const bf16x8*)&Qm[(size_t)(q0 + mf*16 + lr) * DMODEL + t*32 + lg*8];
  f32x4 acc[2][4] = {};
  if (tid < 32){ mls[tid] = -3.0e38f; lls[tid] = 0.0f; }
  __syncthreads();
  const float scale = 0.04419417382415922f;  // 1/sqrt(512)
  for (int j0 = 0; j0 < N_TOK; j0 += 64){
    // stage K tile [64][512]
    #pragma unroll
    for (int i = 0; i < 8; ++i){
      int row = w*8 + i;  // wave-uniform
      async_copy16((char*)&Kls[0][0] + row*1024,
                   Km + (size_t)(j0 + row)*DMODEL + l*8);
    }
    __syncthreads();
    // S = Q K^T (one 16x16 frag per wave, K=512)
    f32x4 s = {};
    #pragma unroll
    for (int t = 0; t < 16; ++t){
      bf16x8 kf = *(const bf16x8*)&Kls[nf*16 + lr][t*32 + lg*8];
      s = mfma16x16x32(qf[t], kf, s);
    }
    #pragma unroll
    for (int r = 0; r < 4; ++r)
      Sls[mf*16 + lg*4 + r][nf*16 + lr] = s[r] * scale;
    __syncthreads();
    // online softmax: 16 lanes per row
    {
      int row = tid >> 4, ci = tid & 15;
      float v0 = Sls[row][ci*4+0], v1 = Sls[row][ci*4+1];
      float v2 = Sls[row][ci*4+2], v3 = Sls[row][ci*4+3];
      float mx = fmaxf(fmaxf(v0, v1), fmaxf(v2, v3));
      #pragma unroll
      for (int dl = 1; dl < 16; dl <<= 1) mx = fmaxf(mx, __shfl_xor(mx, dl));
      float mold = mls[row];
      float mnew = fmaxf(mold, mx);
      float fac  = __expf(mold - mnew);
      float p0 = __expf(v0 - mnew), p1 = __expf(v1 - mnew);
      float p2 = __expf(v2 - mnew), p3 = __expf(v3 - mnew);
      float sum = p0 + p1 + p2 + p3;
      #pragma unroll
      for (int dl = 1; dl < 16; dl <<= 1) sum += __shfl_xor(sum, dl);
      Pls[row][ci*4+0] = (__bf16)p0; Pls[row][ci*4+1] = (__bf16)p1;
      Pls[row][ci*4+2] = (__bf16)p2; Pls[row][ci*4+3] = (__bf16)p3;
      if (ci == 0){ mls[row] = mnew; lls[row] = lls[row]*fac + sum; fls[row] = fac; }
    }
    __syncthreads();
    // rescale acc, then acc += P @ V (B-frags straight from global Vt)
    float f0[2][4];
    #pragma unroll
    for (int mfa = 0; mfa < 2; ++mfa)
      #pragma unroll
      for (int r = 0; r < 4; ++r)
        f0[mfa][r] = fls[mfa*16 + lg*4 + r];
    #pragma unroll
    for (int mfa = 0; mfa < 2; ++mfa)
      #pragma unroll
      for (int nfa = 0; nfa < 4; ++nfa)
        #pragma unroll
        for (int r = 0; r < 4; ++r)
          acc[mfa][nfa][r] *= f0[mfa][r];
    #pragma unroll
    for (int t = 0; t < 2; ++t){
      bf16x8 pf0 = *(const bf16x8*)&Pls[lr     ][t*32 + lg*8];
      bf16x8 pf1 = *(const bf16x8*)&Pls[16 + lr][t*32 + lg*8];
      #pragma unroll
      for (int nfa = 0; nfa < 4; ++nfa){
        bf16x8 vf = *(const bf16x8*)&Vt[(size_t)(d0 + nfa*16 + lr) * N_TOK + j0 + t*32 + lg*8];
        acc[0][nfa] = mfma16x16x32(pf0, vf, acc[0][nfa]);
        acc[1][nfa] = mfma16x16x32(pf1, vf, acc[1][nfa]);
      }
    }
    __syncthreads();
  }
  // epilogue: ctx = acc / l
  #pragma unroll
  for (int mfa = 0; mfa < 2; ++mfa)
    #pragma unroll
    for (int r = 0; r < 4; ++r){
      int row = mfa*16 + lg*4 + r;
      float inv = 1.0f / lls[row];
      #pragma unroll
      for (int nfa = 0; nfa < 4; ++nfa)
        ctx[(size_t)(q0 + row) * DMODEL + d0 + nfa*16 + lr] = (__bf16)(acc[mfa][nfa][r] * inv);
    }
}

// ---------------- MLP head: scores = relu(ctx@W1+b1)@W2 + b2 ----------------
// 64 rows/block, 4 waves; wave w owns h-cols [64w, 64w+64)
__global__ __launch_bounds__(256) void k_mlp(
    const __bf16* __restrict__ ctx, const __bf16* __restrict__ W1t,
    const float* __restrict__ b1, const float* __restrict__ W2,
    const float* __restrict__ b2, float* __restrict__ out)
{
  __shared__ __bf16 Als[64][512];   // 64 KB
  __shared__ float  red[4][64];
  const int tid = threadIdx.x;
  const int w = tid >> 6, l = tid & 63;
  const int lr = l & 15, lg = l >> 4;
  const int m0 = blockIdx.x * 64;
  #pragma unroll
  for (int i = 0; i < 16; ++i){
    int row = w*16 + i;
    async_copy16((char*)&Als[0][0] + row*1024,
                 ctx + (size_t)(m0 + row)*DMODEL + l*8);
  }
  __syncthreads();
  f32x4 acc[4][4] = {};
  for (int t = 0; t < 16; ++t){
    bf16x8 af[4];
    #pragma unroll
    for (int mf2 = 0; mf2 < 4; ++mf2) af[mf2] = *(const bf16x8*)&Als[mf2*16 + lr][t*32 + lg*8];
    #pragma unroll
    for (int nf2 = 0; nf2 < 4; ++nf2){
      bf16x8 bfr = *(const bf16x8*)&W1t[(size_t)(w*64 + nf2*16 + lr)*DMODEL + t*32 + lg*8];
      #pragma unroll
      for (int mf2 = 0; mf2 < 4; ++mf2)
        acc[mf2][nf2] = mfma16x16x32(af[mf2], bfr, acc[mf2][nf2]);
    }
  }
  float part[4][4] = {};
  #pragma unroll
  for (int nf2 = 0; nf2 < 4; ++nf2){
    int col = w*64 + nf2*16 + lr;
    float bb = b1[col], w2v = W2[col];
    #pragma unroll
    for (int mf2 = 0; mf2 < 4; ++mf2)
      #pragma unroll
      for (int r = 0; r < 4; ++r){
        float h = acc[mf2][nf2][r] + bb;
        h = h > 0.0f ? h : 0.0f;
        part[mf2][r] += h * w2v;
      }
  }
  #pragma unroll
  for (int mf2 = 0; mf2 < 4; ++mf2)
    #pragma unroll
    for (int r = 0; r < 4; ++r)
      #pragma unroll
      for (int dl = 1; dl < 16; dl <<= 1)
        part[mf2][r] += __shfl_xor(part[mf2][r], dl);
  if (lr == 0){
    #pragma unroll
    for (int mf2 = 0; mf2 < 4; ++mf2)
      #pragma unroll
      for (int r = 0; r < 4; ++r)
        red[w][mf2*16 + lg*4 + r] = part[mf2][r];
  }
  __syncthreads();
  if (tid < 64)
    out[m0 + tid] = red[0][tid] + red[1][tid] + red[2][tid] + red[3][tid] + b2[0];
}

// ---------------- launcher ----------------
extern "C" void kernel_launch(void* const* d_in, const int* in_sizes, int n_in,
                              void* d_out, int out_size, void* d_ws, size_t ws_size,
                              hipStream_t stream)
{
  const float* x  = (const float*)d_in[0];
  const float* Wq = (const float*)d_in[1];
  const float* bq = (const float*)d_in[2];
  const float* Wk = (const float*)d_in[3];
  const float* bk = (const float*)d_in[4];
  const float* Wv = (const float*)d_in[5];
  const float* bv = (const float*)d_in[6];
  const float* W1 = (const float*)d_in[7];
  const float* b1 = (const float*)d_in[8];
  const float* W2 = (const float*)d_in[9];
  const float* b2 = (const float*)d_in[10];
  float* out = (float*)d_out;
  char* ws = (char*)d_ws;
  // workspace layout (bytes)
  __bf16* xb   = (__bf16*)(ws + 0);          // x bf16           16 MB
  __bf16* qb   = (__bf16*)(ws + 16777216);   // Q [8192][512]     8 MB
  __bf16* kb   = (__bf16*)(ws + 25165824);   // K [8192][512]     8 MB
  __bf16* vtb  = (__bf16*)(ws + 33554432);   // V^T [512][8192]   8 MB
  __bf16* ctxb = (__bf16*)(ws + 41943040);   // ctx [8192][512]   8 MB
  __bf16* wqt  = (__bf16*)(ws + 50331648);   // Wq^T [512][1024]  1 MB
  __bf16* wkt  = (__bf16*)(ws + 51380224);
  __bf16* wvt  = (__bf16*)(ws + 52428800);
  __bf16* w1t  = (__bf16*)(ws + 53477376);   // W1^T [256][512]

  k_cvt<<<2048, 256, 0, stream>>>(x, xb, N_TOK*INDIM/4);
  k_tcvt<<<512, 256, 0, stream>>>(Wq, wqt, INDIM, DMODEL);
  k_tcvt<<<512, 256, 0, stream>>>(Wk, wkt, INDIM, DMODEL);
  k_tcvt<<<512, 256, 0, stream>>>(Wv, wvt, INDIM, DMODEL);
  k_tcvt<<<256, 256, 0, stream>>>(W1, w1t, DMODEL, DMODEL/2);

  // Q = x@Wq + bq (col bias); K likewise; V^T = Wv^T @ x^T + bv (row bias)
  k_gemm_bt<0><<<dim3(N_TOK/128, DMODEL/128), 256, 0, stream>>>(xb, wqt, bq, qb, N_TOK, DMODEL, INDIM);
  k_gemm_bt<0><<<dim3(N_TOK/128, DMODEL/128), 256, 0, stream>>>(xb, wkt, bk, kb, N_TOK, DMODEL, INDIM);
  k_gemm_bt<1><<<dim3(DMODEL/128, N_TOK/128), 256, 0, stream>>>(wvt, xb, bv, vtb, DMODEL, N_TOK, INDIM);

  k_flash<<<N_TOK/32, 512, 0, stream>>>(qb, kb, vtb, ctxb);
  k_mlp<<<N_TOK/64, 256, 0, stream>>>(ctxb, w1t, b1, W2, b2, out);

  (void)in_sizes; (void)n_in; (void)out_size; (void)ws_size;
}

// Round 2
// 512.816 us; speedup vs baseline: 1.5614x; 1.5614x over previous
//
#include <hip/hip_runtime.h>
#include <hip/hip_bf16.h>
#include <cstdint>
#include <cstddef>

typedef float  f32x4  __attribute__((ext_vector_type(4)));
typedef __bf16 bf16x8 __attribute__((ext_vector_type(8)));
typedef __bf16 bf16x4 __attribute__((ext_vector_type(4)));

#define N_TOK  8192
#define INDIM  1024
#define DMODEL 512

__device__ __forceinline__ f32x4 mfma16x16x32(bf16x8 a, bf16x8 b, f32x4 c){
  return __builtin_amdgcn_mfma_f32_16x16x32_bf16(a, b, c, 0, 0, 0);
}

// async global->LDS, 16B per lane; lds base wave-uniform, dest = base + lane*16
__device__ __forceinline__ void async_copy16(void* lds, const void* g){
  __builtin_amdgcn_global_load_lds((__attribute__((address_space(1))) void*)g,
                                   (__attribute__((address_space(3))) void*)lds,
                                   16, 0, 0);
}

// ---------------- convert / transpose ----------------
__global__ void k_cvt(const float* __restrict__ in, __bf16* __restrict__ out, int n4){
  int stride = gridDim.x * blockDim.x;
  for (int i = blockIdx.x * blockDim.x + threadIdx.x; i < n4; i += stride){
    f32x4 v = ((const f32x4*)in)[i];
    bf16x4 o;
    o[0]=(__bf16)v[0]; o[1]=(__bf16)v[1]; o[2]=(__bf16)v[2]; o[3]=(__bf16)v[3];
    ((bf16x4*)out)[i] = o;
  }
}

// W [Kd][Nd] f32 -> Wt [Nd][Kd] bf16
__global__ void k_tcvt(const float* __restrict__ W, __bf16* __restrict__ Wt, int Kd, int Nd){
  int total = Kd * Nd;
  int stride = gridDim.x * blockDim.x;
  for (int i = blockIdx.x * blockDim.x + threadIdx.x; i < total; i += stride){
    int k = i / Nd, n = i - k * Nd;
    Wt[(size_t)n * Kd + k] = (__bf16)W[i];
  }
}

// ---------------- GEMM: C[M,N] = A[M,K] @ Bt[N,K]^T + bias ----------------
template<int BIAS_ROW>
__global__ __launch_bounds__(256) void k_gemm_bt(
    const __bf16* __restrict__ A, const __bf16* __restrict__ Bt,
    const float* __restrict__ bias, __bf16* __restrict__ C,
    int M, int N, int K)
{
  __shared__ __bf16 Als[128][32];
  __shared__ __bf16 Bls[128][32];
  const int tid = threadIdx.x;
  const int w = tid >> 6, l = tid & 63;
  const int lr = l & 15, lg = l >> 4;
  const int wr = w >> 1, wc = w & 1;
  const int m0 = blockIdx.x * 128, n0 = blockIdx.y * 128;
  const int srow = l >> 2;
  const int skof = (l & 3) * 8;
  f32x4 acc[4][4] = {};
  for (int k0 = 0; k0 < K; k0 += 32){
    #pragma unroll
    for (int i = 0; i < 2; ++i){
      int c = i * 4 + w;
      async_copy16((char*)&Als[0][0] + c * 1024,
                   A  + (size_t)(m0 + c*16 + srow) * K + k0 + skof);
      async_copy16((char*)&Bls[0][0] + c * 1024,
                   Bt + (size_t)(n0 + c*16 + srow) * K + k0 + skof);
    }
    __syncthreads();
    bf16x8 af[4], bfv[4];
    #pragma unroll
    for (int mf = 0; mf < 4; ++mf) af[mf]  = *(const bf16x8*)&Als[wr*64 + mf*16 + lr][lg*8];
    #pragma unroll
    for (int nf = 0; nf < 4; ++nf) bfv[nf] = *(const bf16x8*)&Bls[wc*64 + nf*16 + lr][lg*8];
    #pragma unroll
    for (int mf = 0; mf < 4; ++mf)
      #pragma unroll
      for (int nf = 0; nf < 4; ++nf)
        acc[mf][nf] = mfma16x16x32(af[mf], bfv[nf], acc[mf][nf]);
    __syncthreads();
  }
  #pragma unroll
  for (int mf = 0; mf < 4; ++mf)
    #pragma unroll
    for (int nf = 0; nf < 4; ++nf)
      #pragma unroll
      for (int r = 0; r < 4; ++r){
        int row = m0 + wr*64 + mf*16 + lg*4 + r;
        int col = n0 + wc*64 + nf*16 + lr;
        float v = acc[mf][nf][r] + (BIAS_ROW ? bias[row] : bias[col]);
        C[(size_t)row * N + col] = (__bf16)v;
      }
}

// ---------------- flash attention (v2) ----------------
// BQ=32, BK=64, 8 waves. QK: wave (nf=w&3, dh=w>>2) computes partial S over
// D-half dh for key-cols nf*16..+15, both 16-row Q strips reuse each kf read.
// All LDS tiles XOR-swizzled (byte ^= (row&7)<<4). 2 barriers/iter:
//   QK -> writeS -> sync1 -> {stage K(j+1) | prefetch V(kt0) | softmax} -> sync2
//   -> rescale + PV (prefetch V(kt1) inside).
__global__ __launch_bounds__(512, 2) void k_flash(
    const __bf16* __restrict__ Qm, const __bf16* __restrict__ Km,
    const __bf16* __restrict__ Vt, __bf16* __restrict__ ctx)
{
  __shared__ __bf16 Kls[64*512];    // 64 KB, swizzled
  __shared__ float  SP[2*32*64];    // 16 KB partial S, swizzled
  __shared__ __bf16 Pls[32*64];     // 4 KB, swizzled
  __shared__ float  mls[32], lls[32], fls[32];
  const int tid = threadIdx.x;
  const int w = tid >> 6, l = tid & 63;
  const int lr = l & 15, lg = l >> 4;
  const int q0 = blockIdx.x * 32;
  const int nf = w & 3, dh = w >> 2;
  const int d0 = w * 64;
  const int r7l = lr & 7;
  // Q fragments: strips mf=0,1; t-range dh*8..dh*8+7
  bf16x8 qf[2][8];
  #pragma unroll
  for (int mf = 0; mf < 2; ++mf)
    #pragma unroll
    for (int tt = 0; tt < 8; ++tt)
      qf[mf][tt] = *(const bf16x8*)&Qm[(size_t)(q0 + mf*16 + lr)*DMODEL + (dh*8+tt)*32 + lg*8];
  f32x4 acc[2][4] = {};
  if (tid < 32){ mls[tid] = -3.0e38f; lls[tid] = 0.0f; }
  // stage tile 0 (swizzled source, linear LDS dest)
  #pragma unroll
  for (int i = 0; i < 8; ++i){
    int row = w*8 + i;
    async_copy16((char*)Kls + row*1024,
                 Km + (size_t)row*DMODEL + ((l*8) ^ ((row&7)*8)));
  }
  __syncthreads();
  const float scale = 0.04419417382415922f;  // 1/sqrt(512)
  for (int j0 = 0; j0 < N_TOK; j0 += 64){
    // ---- QK: partial S over D-half, kf reused by both strips ----
    f32x4 s0 = {}, s1 = {};
    const int krow = nf*16 + lr;
    #pragma unroll
    for (int tt = 0; tt < 8; ++tt){
      int cb = (dh*8 + tt)*32 + lg*8;
      bf16x8 kf = *(const bf16x8*)&Kls[krow*512 + (cb ^ (r7l*8))];
      s0 = mfma16x16x32(qf[0][tt], kf, s0);
      s1 = mfma16x16x32(qf[1][tt], kf, s1);
    }
    #pragma unroll
    for (int r = 0; r < 4; ++r){
      int row0 = lg*4 + r, row1 = 16 + lg*4 + r;
      int col = nf*16 + lr;
      SP[dh*2048 + row0*64 + (col ^ ((row0&7)<<2))] = s0[r];
      SP[dh*2048 + row1*64 + (col ^ ((row1&7)<<2))] = s1[r];
    }
    __syncthreads();  // sync1: S visible, Kls free
    // ---- stage next K tile (overlaps softmax; drains at sync2) ----
    if (j0 + 64 < N_TOK){
      #pragma unroll
      for (int i = 0; i < 8; ++i){
        int row = w*8 + i;
        async_copy16((char*)Kls + row*1024,
                     Km + (size_t)(j0 + 64 + row)*DMODEL + ((l*8) ^ ((row&7)*8)));
      }
    }
    // ---- prefetch V (kt=0) into regs ----
    bf16x8 vf0[4];
    #pragma unroll
    for (int nfa = 0; nfa < 4; ++nfa)
      vf0[nfa] = *(const bf16x8*)&Vt[(size_t)(d0 + nfa*16 + lr)*N_TOK + j0 + lg*8];
    // ---- softmax: 16 lanes/row ----
    {
      int row = tid >> 4, ci = tid & 15;
      int r7 = row & 7;
      f32x4 a = *(const f32x4*)&SP[       row*64 + ((ci*4) ^ (r7<<2))];
      f32x4 b = *(const f32x4*)&SP[2048 + row*64 + ((ci*4) ^ (r7<<2))];
      float v0 = (a[0]+b[0])*scale, v1 = (a[1]+b[1])*scale;
      float v2 = (a[2]+b[2])*scale, v3 = (a[3]+b[3])*scale;
      float mx = fmaxf(fmaxf(v0, v1), fmaxf(v2, v3));
      #pragma unroll
      for (int dl = 1; dl < 16; dl <<= 1) mx = fmaxf(mx, __shfl_xor(mx, dl));
      float mold = mls[row];
      float mnew = fmaxf(mold, mx);
      float fac  = __expf(mold - mnew);
      float p0 = __expf(v0 - mnew), p1 = __expf(v1 - mnew);
      float p2 = __expf(v2 - mnew), p3 = __expf(v3 - mnew);
      float sum = p0 + p1 + p2 + p3;
      #pragma unroll
      for (int dl = 1; dl < 16; dl <<= 1) sum += __shfl_xor(sum, dl);
      bf16x4 pb; pb[0]=(__bf16)p0; pb[1]=(__bf16)p1; pb[2]=(__bf16)p2; pb[3]=(__bf16)p3;
      *(bf16x4*)&Pls[row*64 + ((ci*4) ^ (r7<<3))] = pb;
      if (ci == 0){ mls[row] = mnew; lls[row] = lls[row]*fac + sum; fls[row] = fac; }
    }
    __syncthreads();  // sync2: P + m/l/f visible; staging + vf0 drained
    // ---- rescale acc ----
    float fr[2][4];
    #pragma unroll
    for (int mfa = 0; mfa < 2; ++mfa)
      #pragma unroll
      for (int r = 0; r < 4; ++r)
        fr[mfa][r] = fls[mfa*16 + lg*4 + r];
    #pragma unroll
    for (int mfa = 0; mfa < 2; ++mfa)
      #pragma unroll
      for (int nfa = 0; nfa < 4; ++nfa)
        #pragma unroll
        for (int r = 0; r < 4; ++r)
          acc[mfa][nfa][r] *= fr[mfa][r];
    // ---- PV kt=0 (prefetch kt=1 in flight) ----
    bf16x8 pf0 = *(const bf16x8*)&Pls[(lr     )*64 + ((lg*8) ^ (r7l*8))];
    bf16x8 pf1 = *(const bf16x8*)&Pls[(16 + lr)*64 + ((lg*8) ^ (r7l*8))];
    bf16x8 vf1[4];
    #pragma unroll
    for (int nfa = 0; nfa < 4; ++nfa)
      vf1[nfa] = *(const bf16x8*)&Vt[(size_t)(d0 + nfa*16 + lr)*N_TOK + j0 + 32 + lg*8];
    #pragma unroll
    for (int nfa = 0; nfa < 4; ++nfa){
      acc[0][nfa] = mfma16x16x32(pf0, vf0[nfa], acc[0][nfa]);
      acc[1][nfa] = mfma16x16x32(pf1, vf0[nfa], acc[1][nfa]);
    }
    // ---- PV kt=1 ----
    bf16x8 pf0b = *(const bf16x8*)&Pls[(lr     )*64 + ((32 + lg*8) ^ (r7l*8))];
    bf16x8 pf1b = *(const bf16x8*)&Pls[(16 + lr)*64 + ((32 + lg*8) ^ (r7l*8))];
    #pragma unroll
    for (int nfa = 0; nfa < 4; ++nfa){
      acc[0][nfa] = mfma16x16x32(pf0b, vf1[nfa], acc[0][nfa]);
      acc[1][nfa] = mfma16x16x32(pf1b, vf1[nfa], acc[1][nfa]);
    }
  }
  // ---- epilogue: ctx = acc / l ----
  #pragma unroll
  for (int mfa = 0; mfa < 2; ++mfa)
    #pragma unroll
    for (int r = 0; r < 4; ++r){
      int row = mfa*16 + lg*4 + r;
      float inv = 1.0f / lls[row];
      #pragma unroll
      for (int nfa = 0; nfa < 4; ++nfa)
        ctx[(size_t)(q0 + row)*DMODEL + d0 + nfa*16 + lr] = (__bf16)(acc[mfa][nfa][r] * inv);
    }
}

// ---------------- MLP head ----------------
__global__ __launch_bounds__(256) void k_mlp(
    const __bf16* __restrict__ ctx, const __bf16* __restrict__ W1t,
    const float* __restrict__ b1, const float* __restrict__ W2,
    const float* __restrict__ b2, float* __restrict__ out)
{
  __shared__ __bf16 Als[64][512];
  __shared__ float  red[4][64];
  const int tid = threadIdx.x;
  const int w = tid >> 6, l = tid & 63;
  const int lr = l & 15, lg = l >> 4;
  const int m0 = blockIdx.x * 64;
  #pragma unroll
  for (int i = 0; i < 16; ++i){
    int row = w*16 + i;
    async_copy16((char*)&Als[0][0] + row*1024,
                 ctx + (size_t)(m0 + row)*DMODEL + l*8);
  }
  __syncthreads();
  f32x4 acc[4][4] = {};
  for (int t = 0; t < 16; ++t){
    bf16x8 af[4];
    #pragma unroll
    for (int mf2 = 0; mf2 < 4; ++mf2) af[mf2] = *(const bf16x8*)&Als[mf2*16 + lr][t*32 + lg*8];
    #pragma unroll
    for (int nf2 = 0; nf2 < 4; ++nf2){
      bf16x8 bfr = *(const bf16x8*)&W1t[(size_t)(w*64 + nf2*16 + lr)*DMODEL + t*32 + lg*8];
      #pragma unroll
      for (int mf2 = 0; mf2 < 4; ++mf2)
        acc[mf2][nf2] = mfma16x16x32(af[mf2], bfr, acc[mf2][nf2]);
    }
  }
  float part[4][4] = {};
  #pragma unroll
  for (int nf2 = 0; nf2 < 4; ++nf2){
    int col = w*64 + nf2*16 + lr;
    float bb = b1[col], w2v = W2[col];
    #pragma unroll
    for (int mf2 = 0; mf2 < 4; ++mf2)
      #pragma unroll
      for (int r = 0; r < 4; ++r){
        float h = acc[mf2][nf2][r] + bb;
        h = h > 0.0f ? h : 0.0f;
        part[mf2][r] += h * w2v;
      }
  }
  #pragma unroll
  for (int mf2 = 0; mf2 < 4; ++mf2)
    #pragma unroll
    for (int r = 0; r < 4; ++r)
      #pragma unroll
      for (int dl = 1; dl < 16; dl <<= 1)
        part[mf2][r] += __shfl_xor(part[mf2][r], dl);
  if (lr == 0){
    #pragma unroll
    for (int mf2 = 0; mf2 < 4; ++mf2)
      #pragma unroll
      for (int r = 0; r < 4; ++r)
        red[w][mf2*16 + lg*4 + r] = part[mf2][r];
  }
  __syncthreads();
  if (tid < 64)
    out[m0 + tid] = red[0][tid] + red[1][tid] + red[2][tid] + red[3][tid] + b2[0];
}

// ---------------- launcher ----------------
extern "C" void kernel_launch(void* const* d_in, const int* in_sizes, int n_in,
                              void* d_out, int out_size, void* d_ws, size_t ws_size,
                              hipStream_t stream)
{
  const float* x  = (const float*)d_in[0];
  const float* Wq = (const float*)d_in[1];
  const float* bq = (const float*)d_in[2];
  const float* Wk = (const float*)d_in[3];
  const float* bk = (const float*)d_in[4];
  const float* Wv = (const float*)d_in[5];
  const float* bv = (const float*)d_in[6];
  const float* W1 = (const float*)d_in[7];
  const float* b1 = (const float*)d_in[8];
  const float* W2 = (const float*)d_in[9];
  const float* b2 = (const float*)d_in[10];
  float* out = (float*)d_out;
  char* ws = (char*)d_ws;
  __bf16* xb   = (__bf16*)(ws + 0);
  __bf16* qb   = (__bf16*)(ws + 16777216);
  __bf16* kb   = (__bf16*)(ws + 25165824);
  __bf16* vtb  = (__bf16*)(ws + 33554432);
  __bf16* ctxb = (__bf16*)(ws + 41943040);
  __bf16* wqt  = (__bf16*)(ws + 50331648);
  __bf16* wkt  = (__bf16*)(ws + 51380224);
  __bf16* wvt  = (__bf16*)(ws + 52428800);
  __bf16* w1t  = (__bf16*)(ws + 53477376);

  k_cvt<<<2048, 256, 0, stream>>>(x, xb, N_TOK*INDIM/4);
  k_tcvt<<<512, 256, 0, stream>>>(Wq, wqt, INDIM, DMODEL);
  k_tcvt<<<512, 256, 0, stream>>>(Wk, wkt, INDIM, DMODEL);
  k_tcvt<<<512, 256, 0, stream>>>(Wv, wvt, INDIM, DMODEL);
  k_tcvt<<<256, 256, 0, stream>>>(W1, w1t, DMODEL, DMODEL/2);

  k_gemm_bt<0><<<dim3(N_TOK/128, DMODEL/128), 256, 0, stream>>>(xb, wqt, bq, qb, N_TOK, DMODEL, INDIM);
  k_gemm_bt<0><<<dim3(N_TOK/128, DMODEL/128), 256, 0, stream>>>(xb, wkt, bk, kb, N_TOK, DMODEL, INDIM);
  k_gemm_bt<1><<<dim3(DMODEL/128, N_TOK/128), 256, 0, stream>>>(wvt, xb, bv, vtb, DMODEL, N_TOK, INDIM);

  k_flash<<<N_TOK/32, 512, 0, stream>>>(qb, kb, vtb, ctxb);
  k_mlp<<<N_TOK/64, 256, 0, stream>>>(ctxb, w1t, b1, W2, b2, out);

  (void)in_sizes; (void)n_in; (void)out_size; (void)ws_size;
}

// Round 3
// 476.111 us; speedup vs baseline: 1.6818x; 1.0771x over previous
//
#include <hip/hip_runtime.h>
#include <hip/hip_bf16.h>
#include <cstdint>
#include <cstddef>

typedef float  f32x4  __attribute__((ext_vector_type(4)));
typedef __bf16 bf16x8 __attribute__((ext_vector_type(8)));
typedef __bf16 bf16x4 __attribute__((ext_vector_type(4)));

#define N_TOK  8192
#define INDIM  1024
#define DMODEL 512
#define SPLIT  2
#define KEYS_PER (N_TOK / SPLIT)   // 4096

__device__ __forceinline__ f32x4 mfma16x16x32(bf16x8 a, bf16x8 b, f32x4 c){
  return __builtin_amdgcn_mfma_f32_16x16x32_bf16(a, b, c, 0, 0, 0);
}

__device__ __forceinline__ void async_copy16(void* lds, const void* g){
  __builtin_amdgcn_global_load_lds((__attribute__((address_space(1))) void*)g,
                                   (__attribute__((address_space(3))) void*)lds,
                                   16, 0, 0);
}

// ---------------- convert / transpose ----------------
__global__ void k_cvt(const float* __restrict__ in, __bf16* __restrict__ out, int n4){
  int stride = gridDim.x * blockDim.x;
  for (int i = blockIdx.x * blockDim.x + threadIdx.x; i < n4; i += stride){
    f32x4 v = ((const f32x4*)in)[i];
    bf16x4 o;
    o[0]=(__bf16)v[0]; o[1]=(__bf16)v[1]; o[2]=(__bf16)v[2]; o[3]=(__bf16)v[3];
    ((bf16x4*)out)[i] = o;
  }
}

__global__ void k_tcvt(const float* __restrict__ W, __bf16* __restrict__ Wt, int Kd, int Nd){
  int total = Kd * Nd;
  int stride = gridDim.x * blockDim.x;
  for (int i = blockIdx.x * blockDim.x + threadIdx.x; i < total; i += stride){
    int k = i / Nd, n = i - k * Nd;
    Wt[(size_t)n * Kd + k] = (__bf16)W[i];
  }
}

// ---------------- GEMM: C[M,N] = A[M,K] @ Bt[N,K]^T + bias ----------------
template<int BIAS_ROW>
__global__ __launch_bounds__(256) void k_gemm_bt(
    const __bf16* __restrict__ A, const __bf16* __restrict__ Bt,
    const float* __restrict__ bias, __bf16* __restrict__ C,
    int M, int N, int K)
{
  __shared__ __bf16 Als[128][32];
  __shared__ __bf16 Bls[128][32];
  const int tid = threadIdx.x;
  const int w = tid >> 6, l = tid & 63;
  const int lr = l & 15, lg = l >> 4;
  const int wr = w >> 1, wc = w & 1;
  const int m0 = blockIdx.x * 128, n0 = blockIdx.y * 128;
  const int srow = l >> 2;
  const int skof = (l & 3) * 8;
  f32x4 acc[4][4] = {};
  for (int k0 = 0; k0 < K; k0 += 32){
    #pragma unroll
    for (int i = 0; i < 2; ++i){
      int c = i * 4 + w;
      async_copy16((char*)&Als[0][0] + c * 1024,
                   A  + (size_t)(m0 + c*16 + srow) * K + k0 + skof);
      async_copy16((char*)&Bls[0][0] + c * 1024,
                   Bt + (size_t)(n0 + c*16 + srow) * K + k0 + skof);
    }
    __syncthreads();
    bf16x8 af[4], bfv[4];
    #pragma unroll
    for (int mf = 0; mf < 4; ++mf) af[mf]  = *(const bf16x8*)&Als[wr*64 + mf*16 + lr][lg*8];
    #pragma unroll
    for (int nf = 0; nf < 4; ++nf) bfv[nf] = *(const bf16x8*)&Bls[wc*64 + nf*16 + lr][lg*8];
    #pragma unroll
    for (int mf = 0; mf < 4; ++mf)
      #pragma unroll
      for (int nf = 0; nf < 4; ++nf)
        acc[mf][nf] = mfma16x16x32(af[mf], bfv[nf], acc[mf][nf]);
    __syncthreads();
  }
  #pragma unroll
  for (int mf = 0; mf < 4; ++mf)
    #pragma unroll
    for (int nf = 0; nf < 4; ++nf)
      #pragma unroll
      for (int r = 0; r < 4; ++r){
        int row = m0 + wr*64 + mf*16 + lg*4 + r;
        int col = n0 + wc*64 + nf*16 + lr;
        float v = acc[mf][nf][r] + (BIAS_ROW ? bias[row] : bias[col]);
        C[(size_t)row * N + col] = (__bf16)v;
      }
}

// ---------------- flash attention v3 ----------------
// BQ=64, 2-way key split, 8 waves, NO K/V LDS staging (direct global, L2-hit).
// QK: wave (mf2=w&1, nf2=(w>>1)&1, dh=w>>2): rows mf2*32+{0,16}, cols nf2*32+{0,16},
//     D-half dh. Partial S summed across dh planes in softmax (8 lanes/row).
// PV: wave w owns output cols w*64..+63, acc[4 strips][4 colfrags].
// LDS: SP f32[2][64][64] (32KB, swz ^((row&7)<<2) elems) + P bf16[64][64]
//      (8KB, swz ^((row&7)<<3) elems) + m/l/f[64].
__global__ __launch_bounds__(512, 2) void k_flash(
    const __bf16* __restrict__ Qm, const __bf16* __restrict__ Km,
    const __bf16* __restrict__ Vt, __bf16* __restrict__ O0,
    __bf16* __restrict__ O1, float* __restrict__ mA, float* __restrict__ lA)
{
  __shared__ float  SP[2*64*64];    // 32 KB
  __shared__ __bf16 Pls[64*64];     // 8 KB
  __shared__ float  mls[64], lls[64], fls[64];
  const int tid = threadIdx.x;
  const int w = tid >> 6, l = tid & 63;
  const int lr = l & 15, lg = l >> 4;
  const int q0 = blockIdx.x * 64;
  const int sp = blockIdx.y;
  const int kbase = sp * KEYS_PER;
  const int mf2 = w & 1, nf2 = (w >> 1) & 1, dh = w >> 2;
  const int d0 = w * 64;
  // Q fragments: 2 strips (within mf2 half) x 8 K-chunks of D-half dh
  bf16x8 qf[2][8];
  #pragma unroll
  for (int st = 0; st < 2; ++st)
    #pragma unroll
    for (int tt = 0; tt < 8; ++tt)
      qf[st][tt] = *(const bf16x8*)&Qm[(size_t)(q0 + mf2*32 + st*16 + lr)*DMODEL
                                       + dh*256 + tt*32 + lg*8];
  f32x4 acc[4][4] = {};
  if (tid < 64){ mls[tid] = -3.0e38f; lls[tid] = 0.0f; }
  __syncthreads();
  const float scale = 0.04419417382415922f;  // 1/sqrt(512)
  for (int j0 = 0; j0 < KEYS_PER; j0 += 64){
    const __bf16* Kp = Km + (size_t)(kbase + j0) * DMODEL;
    // ---- QK: direct-global K frags, 4-way reuse per load pair ----
    f32x4 s00 = {}, s01 = {}, s10 = {}, s11 = {};
    #pragma unroll
    for (int tt = 0; tt < 8; ++tt){
      int coff = dh*256 + tt*32 + lg*8;
      bf16x8 k0 = *(const bf16x8*)&Kp[(size_t)(nf2*32 +      lr)*DMODEL + coff];
      bf16x8 k1 = *(const bf16x8*)&Kp[(size_t)(nf2*32 + 16 + lr)*DMODEL + coff];
      s00 = mfma16x16x32(qf[0][tt], k0, s00);
      s10 = mfma16x16x32(qf[1][tt], k0, s10);
      s01 = mfma16x16x32(qf[0][tt], k1, s01);
      s11 = mfma16x16x32(qf[1][tt], k1, s11);
    }
    // ---- prefetch V frags early (drain under S-write + sync1) ----
    const __bf16* Vp = Vt + kbase + j0;
    bf16x8 vf[2][4];
    #pragma unroll
    for (int kt = 0; kt < 2; ++kt)
      #pragma unroll
      for (int nfa = 0; nfa < 4; ++nfa)
        vf[kt][nfa] = *(const bf16x8*)&Vp[(size_t)(d0 + nfa*16 + lr)*N_TOK
                                          + kt*32 + lg*8];
    // ---- write partial S (swizzled) ----
    #pragma unroll
    for (int r = 0; r < 4; ++r){
      int rowA = mf2*32 +      lg*4 + r;
      int rowB = mf2*32 + 16 + lg*4 + r;
      int colA = nf2*32 + lr, colB = nf2*32 + 16 + lr;
      SP[dh*4096 + rowA*64 + (colA ^ ((rowA&7)<<2))] = s00[r];
      SP[dh*4096 + rowB*64 + (colA ^ ((rowB&7)<<2))] = s10[r];
      SP[dh*4096 + rowA*64 + (colB ^ ((rowA&7)<<2))] = s01[r];
      SP[dh*4096 + rowB*64 + (colB ^ ((rowB&7)<<2))] = s11[r];
    }
    __syncthreads();  // sync1
    // ---- softmax: 8 lanes per row ----
    {
      int row = tid >> 3, ci = tid & 7;
      int sw = (row & 7) << 2;
      f32x4 a0 = *(const f32x4*)&SP[       row*64 + ((ci*8    ) ^ sw)];
      f32x4 a1 = *(const f32x4*)&SP[       row*64 + ((ci*8 + 4) ^ sw)];
      f32x4 b0 = *(const f32x4*)&SP[4096 + row*64 + ((ci*8    ) ^ sw)];
      f32x4 b1 = *(const f32x4*)&SP[4096 + row*64 + ((ci*8 + 4) ^ sw)];
      float v0=(a0[0]+b0[0])*scale, v1=(a0[1]+b0[1])*scale;
      float v2=(a0[2]+b0[2])*scale, v3=(a0[3]+b0[3])*scale;
      float v4=(a1[0]+b1[0])*scale, v5=(a1[1]+b1[1])*scale;
      float v6=(a1[2]+b1[2])*scale, v7=(a1[3]+b1[3])*scale;
      float mx = fmaxf(fmaxf(fmaxf(v0,v1),fmaxf(v2,v3)),
                       fmaxf(fmaxf(v4,v5),fmaxf(v6,v7)));
      #pragma unroll
      for (int dl = 1; dl < 8; dl <<= 1) mx = fmaxf(mx, __shfl_xor(mx, dl));
      float mold = mls[row];
      float mnew = fmaxf(mold, mx);
      float fac  = __expf(mold - mnew);
      float p0=__expf(v0-mnew), p1=__expf(v1-mnew), p2=__expf(v2-mnew), p3=__expf(v3-mnew);
      float p4=__expf(v4-mnew), p5=__expf(v5-mnew), p6=__expf(v6-mnew), p7=__expf(v7-mnew);
      float sum = ((p0+p1)+(p2+p3)) + ((p4+p5)+(p6+p7));
      #pragma unroll
      for (int dl = 1; dl < 8; dl <<= 1) sum += __shfl_xor(sum, dl);
      bf16x8 pb;
      pb[0]=(__bf16)p0; pb[1]=(__bf16)p1; pb[2]=(__bf16)p2; pb[3]=(__bf16)p3;
      pb[4]=(__bf16)p4; pb[5]=(__bf16)p5; pb[6]=(__bf16)p6; pb[7]=(__bf16)p7;
      *(bf16x8*)&Pls[row*64 + ((ci*8) ^ ((row&7)<<3))] = pb;
      if (ci == 0){ mls[row] = mnew; lls[row] = lls[row]*fac + sum; fls[row] = fac; }
    }
    __syncthreads();  // sync2
    // ---- rescale acc ----
    float fr[4][4];
    #pragma unroll
    for (int st = 0; st < 4; ++st)
      #pragma unroll
      for (int r = 0; r < 4; ++r)
        fr[st][r] = fls[st*16 + lg*4 + r];
    #pragma unroll
    for (int st = 0; st < 4; ++st)
      #pragma unroll
      for (int nfa = 0; nfa < 4; ++nfa)
        #pragma unroll
        for (int r = 0; r < 4; ++r)
          acc[st][nfa][r] *= fr[st][r];
    // ---- PV: P from LDS (swz), V from regs ----
    #pragma unroll
    for (int kt = 0; kt < 2; ++kt){
      bf16x8 pf[4];
      #pragma unroll
      for (int st = 0; st < 4; ++st){
        int prow = st*16 + lr;
        pf[st] = *(const bf16x8*)&Pls[prow*64 + ((kt*32 + lg*8) ^ ((prow&7)<<3))];
      }
      #pragma unroll
      for (int st = 0; st < 4; ++st)
        #pragma unroll
        for (int nfa = 0; nfa < 4; ++nfa)
          acc[st][nfa] = mfma16x16x32(pf[st], vf[kt][nfa], acc[st][nfa]);
    }
  }
  // ---- epilogue: normalized partial + stats ----
  __bf16* Op = sp ? O1 : O0;
  #pragma unroll
  for (int st = 0; st < 4; ++st)
    #pragma unroll
    for (int r = 0; r < 4; ++r){
      int row = st*16 + lg*4 + r;
      float inv = 1.0f / lls[row];
      #pragma unroll
      for (int nfa = 0; nfa < 4; ++nfa)
        Op[(size_t)(q0 + row)*DMODEL + d0 + nfa*16 + lr] = (__bf16)(acc[st][nfa][r] * inv);
    }
  if (tid < 64){
    mA[sp*N_TOK + q0 + tid] = mls[tid];
    lA[sp*N_TOK + q0 + tid] = lls[tid];
  }
}

// ---------------- combine the two key-splits ----------------
__global__ __launch_bounds__(256) void k_combine(
    const __bf16* __restrict__ O0, const __bf16* __restrict__ O1,
    const float* __restrict__ mA, const float* __restrict__ lA,
    __bf16* __restrict__ ctx)
{
  int idx = blockIdx.x * 256 + threadIdx.x;       // 8192*64
  int row = idx >> 6, ch = idx & 63;
  float m0 = mA[row], m1 = mA[N_TOK + row];
  float l0 = lA[row], l1 = lA[N_TOK + row];
  float mm = fmaxf(m0, m1);
  float w0 = l0 * __expf(m0 - mm), w1 = l1 * __expf(m1 - mm);
  float inv = 1.0f / (w0 + w1);
  w0 *= inv; w1 *= inv;
  size_t off = (size_t)row * (DMODEL/8) + ch;
  bf16x8 c0 = ((const bf16x8*)O0)[off];
  bf16x8 c1 = ((const bf16x8*)O1)[off];
  bf16x8 o;
  #pragma unroll
  for (int i = 0; i < 8; ++i)
    o[i] = (__bf16)((float)c0[i]*w0 + (float)c1[i]*w1);
  ((bf16x8*)ctx)[off] = o;
}

// ---------------- MLP head ----------------
__global__ __launch_bounds__(256) void k_mlp(
    const __bf16* __restrict__ ctx, const __bf16* __restrict__ W1t,
    const float* __restrict__ b1, const float* __restrict__ W2,
    const float* __restrict__ b2, float* __restrict__ out)
{
  __shared__ __bf16 Als[64][512];
  __shared__ float  red[4][64];
  const int tid = threadIdx.x;
  const int w = tid >> 6, l = tid & 63;
  const int lr = l & 15, lg = l >> 4;
  const int m0 = blockIdx.x * 64;
  #pragma unroll
  for (int i = 0; i < 16; ++i){
    int row = w*16 + i;
    async_copy16((char*)&Als[0][0] + row*1024,
                 ctx + (size_t)(m0 + row)*DMODEL + l*8);
  }
  __syncthreads();
  f32x4 acc[4][4] = {};
  for (int t = 0; t < 16; ++t){
    bf16x8 af[4];
    #pragma unroll
    for (int mf2 = 0; mf2 < 4; ++mf2) af[mf2] = *(const bf16x8*)&Als[mf2*16 + lr][t*32 + lg*8];
    #pragma unroll
    for (int nf2 = 0; nf2 < 4; ++nf2){
      bf16x8 bfr = *(const bf16x8*)&W1t[(size_t)(w*64 + nf2*16 + lr)*DMODEL + t*32 + lg*8];
      #pragma unroll
      for (int mf2 = 0; mf2 < 4; ++mf2)
        acc[mf2][nf2] = mfma16x16x32(af[mf2], bfr, acc[mf2][nf2]);
    }
  }
  float part[4][4] = {};
  #pragma unroll
  for (int nf2 = 0; nf2 < 4; ++nf2){
    int col = w*64 + nf2*16 + lr;
    float bb = b1[col], w2v = W2[col];
    #pragma unroll
    for (int mf2 = 0; mf2 < 4; ++mf2)
      #pragma unroll
      for (int r = 0; r < 4; ++r){
        float h = acc[mf2][nf2][r] + bb;
        h = h > 0.0f ? h : 0.0f;
        part[mf2][r] += h * w2v;
      }
  }
  #pragma unroll
  for (int mf2 = 0; mf2 < 4; ++mf2)
    #pragma unroll
    for (int r = 0; r < 4; ++r)
      #pragma unroll
      for (int dl = 1; dl < 16; dl <<= 1)
        part[mf2][r] += __shfl_xor(part[mf2][r], dl);
  if (lr == 0){
    #pragma unroll
    for (int mf2 = 0; mf2 < 4; ++mf2)
      #pragma unroll
      for (int r = 0; r < 4; ++r)
        red[w][mf2*16 + lg*4 + r] = part[mf2][r];
  }
  __syncthreads();
  if (tid < 64)
    out[m0 + tid] = red[0][tid] + red[1][tid] + red[2][tid] + red[3][tid] + b2[0];
}

// ---------------- launcher ----------------
extern "C" void kernel_launch(void* const* d_in, const int* in_sizes, int n_in,
                              void* d_out, int out_size, void* d_ws, size_t ws_size,
                              hipStream_t stream)
{
  const float* x  = (const float*)d_in[0];
  const float* Wq = (const float*)d_in[1];
  const float* bq = (const float*)d_in[2];
  const float* Wk = (const float*)d_in[3];
  const float* bk = (const float*)d_in[4];
  const float* Wv = (const float*)d_in[5];
  const float* bv = (const float*)d_in[6];
  const float* W1 = (const float*)d_in[7];
  const float* b1 = (const float*)d_in[8];
  const float* W2 = (const float*)d_in[9];
  const float* b2 = (const float*)d_in[10];
  float* out = (float*)d_out;
  char* ws = (char*)d_ws;
  __bf16* xb   = (__bf16*)(ws + 0);          // x bf16 (dead after GEMMs)
  __bf16* qb   = (__bf16*)(ws + 16777216);
  __bf16* kb   = (__bf16*)(ws + 25165824);
  __bf16* vtb  = (__bf16*)(ws + 33554432);
  __bf16* ctxb = (__bf16*)(ws + 41943040);
  __bf16* wqt  = (__bf16*)(ws + 50331648);
  __bf16* wkt  = (__bf16*)(ws + 51380224);
  __bf16* wvt  = (__bf16*)(ws + 52428800);
  __bf16* w1t  = (__bf16*)(ws + 53477376);
  // split-attention partials reuse the dead xb region
  __bf16* O1   = (__bf16*)(ws + 0);          // 8.39 MB
  float*  mA   = (float*)(ws + 8388608);     // 2*8192 f32
  float*  lA   = (float*)(ws + 8454144);     // 2*8192 f32

  k_cvt<<<2048, 256, 0, stream>>>(x, xb, N_TOK*INDIM/4);
  k_tcvt<<<512, 256, 0, stream>>>(Wq, wqt, INDIM, DMODEL);
  k_tcvt<<<512, 256, 0, stream>>>(Wk, wkt, INDIM, DMODEL);
  k_tcvt<<<512, 256, 0, stream>>>(Wv, wvt, INDIM, DMODEL);
  k_tcvt<<<256, 256, 0, stream>>>(W1, w1t, DMODEL, DMODEL/2);

  k_gemm_bt<0><<<dim3(N_TOK/128, DMODEL/128), 256, 0, stream>>>(xb, wqt, bq, qb, N_TOK, DMODEL, INDIM);
  k_gemm_bt<0><<<dim3(N_TOK/128, DMODEL/128), 256, 0, stream>>>(xb, wkt, bk, kb, N_TOK, DMODEL, INDIM);
  k_gemm_bt<1><<<dim3(DMODEL/128, N_TOK/128), 256, 0, stream>>>(wvt, xb, bv, vtb, DMODEL, N_TOK, INDIM);

  k_flash<<<dim3(N_TOK/64, SPLIT), 512, 0, stream>>>(qb, kb, vtb, ctxb, O1, mA, lA);
  k_combine<<<N_TOK*64/256, 256, 0, stream>>>(ctxb, O1, mA, lA, ctxb);
  k_mlp<<<N_TOK/64, 256, 0, stream>>>(ctxb, w1t, b1, W2, b2, out);

  (void)in_sizes; (void)n_in; (void)out_size; (void)ws_size;
}